// Round 7
// baseline (33.940 us; speedup 1.0000x reference)
//
#include <hip/hip_runtime.h>
#include <math.h>

#define EMBED 1280
#define NHEAD 20
#define HDIM 64
#define LENC 8192
#define CHUNK 128               // rows per block (4 waves x 32 rows)
#define NBLK (LENC / CHUNK)     // 64 blocks per head
#define QSCALE 0.125f           // 64^-0.5
#define SHIFT 4.0f              // fixed softmax shift: exp(s-4); |s| <~ 4 for these
                                // inputs, and softmax is invariant to any constant
                                // shift, so no per-head max pass is needed.

// ws layout (floats):
//   [0..19]        S_acc   per-head exp-sum accumulators
//   [32..1311]     o_acc   per-head unnormalized output accumulators (20*64)
//   [2048..3327]   qv      projected+scaled q vector

// ---------------------------------------------------------------------------
// q projection: one row per block, 256 threads, float4 loads.
// Block 0 additionally zeroes the attention accumulators (visible to the next
// kernel via kernel-boundary coherence; proven pattern from round 2).
// ---------------------------------------------------------------------------
__global__ __launch_bounds__(256) void matvec_qproj(
    const float* __restrict__ W, const float* __restrict__ x,
    const float* __restrict__ b, float* __restrict__ ws_base) {
  float* qv = ws_base + 2048;
  if (blockIdx.x == 0) {
#pragma unroll
    for (int idx = threadIdx.x; idx < 32 + NHEAD * HDIM; idx += 256)
      ws_base[idx] = 0.f;
  }
  int row = blockIdx.x;
  int t = threadIdx.x;
  int w = t >> 6, lane = t & 63;
  const float4* Wr = reinterpret_cast<const float4*>(W + (size_t)row * EMBED);
  const float4* x4 = reinterpret_cast<const float4*>(x);
  float4 wv = Wr[t], xv = x4[t];
  float acc = wv.x * xv.x + wv.y * xv.y + wv.z * xv.z + wv.w * xv.w;
  if (t < 64) {
    float4 wv2 = Wr[256 + t], xv2 = x4[256 + t];
    acc += wv2.x * xv2.x + wv2.y * xv2.y + wv2.z * xv2.z + wv2.w * xv2.w;
  }
#pragma unroll
  for (int msk = 32; msk > 0; msk >>= 1) acc += __shfl_xor(acc, msk);
  __shared__ float red[4];
  if (lane == 0) red[w] = acc;
  __syncthreads();
  if (t == 0) qv[row] = QSCALE * (red[0] + red[1] + red[2] + red[3] + b[row]);
}

// ---------------------------------------------------------------------------
// Flash-decode with fixed-shift softmax: each WAVE owns 32 keys (round-4
// structure: 8 K + 8 V float4 in flight/lane, no max pass). Waves LDS-reduce
// within the block, then ONE set of 65 fire-and-forget atomicAdds per block
// into the per-head accumulators. No fences, no atomic loads, no records.
// ---------------------------------------------------------------------------
__global__ __launch_bounds__(256) void attn_partial(
    const float* __restrict__ K, const float* __restrict__ V,
    const float* __restrict__ ws_base) {
  float* S_acc = const_cast<float*>(ws_base);
  float* o_acc = const_cast<float*>(ws_base) + 32;
  const float* qv = ws_base + 2048;

  int blk = blockIdx.x;   // 0..NHEAD*NBLK-1
  int h = blk / NBLK;
  int c = blk % NBLK;
  int tid = threadIdx.x;
  int w = tid >> 6;       // wave 0..3
  int lane = tid & 63;
  int grp = lane >> 4;    // row-group 0..3 within wave
  int l16 = lane & 15;    // float4 index within row

  size_t row0 = (size_t)c * CHUNK + (size_t)w * 32;
  const float4* Kh4 = reinterpret_cast<const float4*>(K + (size_t)h * LENC * HDIM) + row0 * 16;
  const float4* Vh4 = reinterpret_cast<const float4*>(V + (size_t)h * LENC * HDIM) + row0 * 16;
  float4 q4 = reinterpret_cast<const float4*>(qv + h * HDIM)[l16];

  float4 kreg[8], vreg[8];
#pragma unroll
  for (int it = 0; it < 8; ++it) kreg[it] = Kh4[(it * 4 + grp) * 16 + l16];
#pragma unroll
  for (int it = 0; it < 8; ++it) vreg[it] = Vh4[(it * 4 + grp) * 16 + l16];

  // scores for my group's 8 rows (replicated across the group's 16 lanes)
  float s[8];
#pragma unroll
  for (int it = 0; it < 8; ++it) {
    float t = kreg[it].x * q4.x + kreg[it].y * q4.y + kreg[it].z * q4.z + kreg[it].w * q4.w;
    t += __shfl_xor(t, 1);
    t += __shfl_xor(t, 2);
    t += __shfl_xor(t, 4);
    t += __shfl_xor(t, 8);
    s[it] = t;
  }

  // fixed-shift exp + wave exp-sum (no max pass)
  float e[8], ssum = 0.f;
#pragma unroll
  for (int it = 0; it < 8; ++it) { e[it] = expf(s[it] - SHIFT); ssum += e[it]; }
  ssum += __shfl_xor(ssum, 16);
  ssum += __shfl_xor(ssum, 32);

  // P @ V for my group's rows, dims [l16*4, l16*4+4)
  float4 o = make_float4(0.f, 0.f, 0.f, 0.f);
#pragma unroll
  for (int it = 0; it < 8; ++it) {
    o.x += e[it] * vreg[it].x;
    o.y += e[it] * vreg[it].y;
    o.z += e[it] * vreg[it].z;
    o.w += e[it] * vreg[it].w;
  }
#pragma unroll
  for (int msk = 16; msk <= 32; msk <<= 1) {
    o.x += __shfl_xor(o.x, msk);
    o.y += __shfl_xor(o.y, msk);
    o.z += __shfl_xor(o.z, msk);
    o.w += __shfl_xor(o.w, msk);
  }

  // block-level reduce in LDS, then 65 atomics per block
  __shared__ float ov[4][HDIM];
  __shared__ float ssh[4];
  if (grp == 0) {
    ov[w][4 * l16 + 0] = o.x;
    ov[w][4 * l16 + 1] = o.y;
    ov[w][4 * l16 + 2] = o.z;
    ov[w][4 * l16 + 3] = o.w;
    if (l16 == 0) ssh[w] = ssum;
  }
  __syncthreads();
  if (w == 0) {
    float od = ov[0][lane] + ov[1][lane] + ov[2][lane] + ov[3][lane];
    atomicAdd(&o_acc[h * HDIM + lane], od);
    if (lane == 0)
      atomicAdd(&S_acc[h], ssh[0] + ssh[1] + ssh[2] + ssh[3]);
  }
}

// ---------------------------------------------------------------------------
// Fused normalize + output projection: one row per block, 256 threads.
// x[i] = o_acc[i] / S_acc[i/64]; out[row] = W[row,:].x + b[row]
// ---------------------------------------------------------------------------
__global__ __launch_bounds__(256) void matvec_out(
    const float* __restrict__ W, const float* __restrict__ ws_base,
    const float* __restrict__ b, float* __restrict__ out) {
  const float* S_acc = ws_base;
  const float* o_acc = ws_base + 32;
  int row = blockIdx.x;
  int t = threadIdx.x;
  int w = t >> 6, lane = t & 63;
  const float4* Wr = reinterpret_cast<const float4*>(W + (size_t)row * EMBED);
  const float4* o4p = reinterpret_cast<const float4*>(o_acc);

  float4 wv = Wr[t];
  float4 x0 = o4p[t];
  float rS = 1.0f / S_acc[t >> 4];        // head of dims 4t..4t+3
  float acc = (wv.x * x0.x + wv.y * x0.y + wv.z * x0.z + wv.w * x0.w) * rS;
  if (t < 64) {
    float4 wv2 = Wr[256 + t];
    float4 x1 = o4p[256 + t];
    float rS2 = 1.0f / S_acc[16 + (t >> 4)];  // heads 16..19
    acc += (wv2.x * x1.x + wv2.y * x1.y + wv2.z * x1.z + wv2.w * x1.w) * rS2;
  }
#pragma unroll
  for (int msk = 32; msk > 0; msk >>= 1) acc += __shfl_xor(acc, msk);
  __shared__ float red[4];
  if (lane == 0) red[w] = acc;
  __syncthreads();
  if (t == 0) out[row] = red[0] + red[1] + red[2] + red[3] + b[row];
}

// ---------------------------------------------------------------------------

extern "C" void kernel_launch(void* const* d_in, const int* in_sizes, int n_in,
                              void* d_out, int out_size, void* d_ws, size_t ws_size,
                              hipStream_t stream) {
  const float* hs    = (const float*)d_in[0];  // [1280]
  const float* Kc    = (const float*)d_in[1];  // [20,8192,64]
  const float* Vc    = (const float*)d_in[2];  // [20,8192,64]
  const float* q_w   = (const float*)d_in[3];  // [1280,1280]
  const float* q_b   = (const float*)d_in[4];  // [1280]
  const float* out_w = (const float*)d_in[5];  // [1280,1280]
  const float* out_b = (const float*)d_in[6];  // [1280]
  float* out = (float*)d_out;                  // [1280]
  float* ws  = (float*)d_ws;

  // 1. q projection (+ scale); block 0 zeroes the accumulators
  matvec_qproj<<<EMBED, 256, 0, stream>>>(q_w, hs, q_b, ws);
  // 2. flash-decode, fixed-shift softmax, atomic accumulation per head
  attn_partial<<<NHEAD * NBLK, 256, 0, stream>>>(Kc, Vc, ws);
  // 3. fused normalize + output projection
  matvec_out<<<EMBED, 256, 0, stream>>>(out_w, ws, out_b, out);
}

// Round 8
// 29.138 us; speedup vs baseline: 1.1648x; 1.1648x over previous
//
#include <hip/hip_runtime.h>
#include <math.h>

#define EMBED 1280
#define NHEAD 20
#define HDIM 64
#define LENC 8192
#define CHUNK 128               // rows per block (4 independent waves x 32 rows)
#define NBLK (LENC / CHUNK)     // 64 blocks per head
#define NREC 256                // partial records per head (one per wave)
#define PREC 72                 // floats per record: [M,S,pad,pad,o[64]]
#define QSCALE 0.125f           // 64^-0.5

// ---------------------------------------------------------------------------
// matvec: one row per block, 256 threads, float4 loads.
// y[row] = scale * (W[row,:] . x + b[row])
// ---------------------------------------------------------------------------
__global__ __launch_bounds__(256) void matvec_row(
    const float* __restrict__ W, const float* __restrict__ x,
    const float* __restrict__ b, float* __restrict__ y, float scale) {
  int row = blockIdx.x;
  int t = threadIdx.x;
  int w = t >> 6, lane = t & 63;
  const float4* Wr = reinterpret_cast<const float4*>(W + (size_t)row * EMBED);
  const float4* x4 = reinterpret_cast<const float4*>(x);
  float4 wv = Wr[t], xv = x4[t];
  float acc = wv.x * xv.x + wv.y * xv.y + wv.z * xv.z + wv.w * xv.w;
  if (t < 64) {
    float4 wv2 = Wr[256 + t], xv2 = x4[256 + t];
    acc += wv2.x * xv2.x + wv2.y * xv2.y + wv2.z * xv2.z + wv2.w * xv2.w;
  }
#pragma unroll
  for (int msk = 32; msk > 0; msk >>= 1) acc += __shfl_xor(acc, msk);
  __shared__ float red[4];
  if (lane == 0) red[w] = acc;
  __syncthreads();
  if (t == 0) y[row] = scale * (red[0] + red[1] + red[2] + red[3] + b[row]);
}

// ---------------------------------------------------------------------------
// Flash-decode partial: each WAVE independently owns 32 keys.
// No LDS, no __syncthreads, no fences. 16 float4 loads in flight per lane.
// 16 lanes span one 64-float row; lane group grp handles rows it*4+grp.
// Record per wave: [M, S, pad, pad, o[64]] (o unnormalized).
// __expf: hardware v_exp_f32 (~2 instr) instead of libm expf (~20+) --
// the exp chain sits on the critical path between score-reduce and PV.
// ---------------------------------------------------------------------------
__global__ __launch_bounds__(256) void attn_partial(
    const float* __restrict__ K, const float* __restrict__ V,
    const float* __restrict__ q, float* __restrict__ part) {
  int blk = blockIdx.x;   // 0..NHEAD*NBLK-1
  int h = blk / NBLK;
  int c = blk % NBLK;
  int tid = threadIdx.x;
  int w = tid >> 6;       // wave 0..3
  int lane = tid & 63;
  int grp = lane >> 4;    // row-group 0..3 within wave
  int l16 = lane & 15;    // float4 index within row

  size_t row0 = (size_t)c * CHUNK + (size_t)w * 32;
  const float4* Kh4 = reinterpret_cast<const float4*>(K + (size_t)h * LENC * HDIM) + row0 * 16;
  const float4* Vh4 = reinterpret_cast<const float4*>(V + (size_t)h * LENC * HDIM) + row0 * 16;
  float4 qv = reinterpret_cast<const float4*>(q + h * HDIM)[l16];

  float4 kreg[8], vreg[8];
#pragma unroll
  for (int it = 0; it < 8; ++it) kreg[it] = Kh4[(it * 4 + grp) * 16 + l16];
#pragma unroll
  for (int it = 0; it < 8; ++it) vreg[it] = Vh4[(it * 4 + grp) * 16 + l16];

  float s[8];
#pragma unroll
  for (int it = 0; it < 8; ++it) {
    float t = kreg[it].x * qv.x + kreg[it].y * qv.y + kreg[it].z * qv.z + kreg[it].w * qv.w;
    t += __shfl_xor(t, 1);
    t += __shfl_xor(t, 2);
    t += __shfl_xor(t, 4);
    t += __shfl_xor(t, 8);
    s[it] = t;
  }

  float m = s[0];
#pragma unroll
  for (int it = 1; it < 8; ++it) m = fmaxf(m, s[it]);
  m = fmaxf(m, __shfl_xor(m, 16));
  m = fmaxf(m, __shfl_xor(m, 32));

  float e[8], ssum = 0.f;
#pragma unroll
  for (int it = 0; it < 8; ++it) { e[it] = __expf(s[it] - m); ssum += e[it]; }
  ssum += __shfl_xor(ssum, 16);
  ssum += __shfl_xor(ssum, 32);

  float4 o = make_float4(0.f, 0.f, 0.f, 0.f);
#pragma unroll
  for (int it = 0; it < 8; ++it) {
    o.x += e[it] * vreg[it].x;
    o.y += e[it] * vreg[it].y;
    o.z += e[it] * vreg[it].z;
    o.w += e[it] * vreg[it].w;
  }
#pragma unroll
  for (int msk = 16; msk <= 32; msk <<= 1) {
    o.x += __shfl_xor(o.x, msk);
    o.y += __shfl_xor(o.y, msk);
    o.z += __shfl_xor(o.z, msk);
    o.w += __shfl_xor(o.w, msk);
  }

  float* p = part + (size_t)(h * NREC + c * 4 + w) * PREC;
  if (grp == 0) {
    if (l16 == 0) { p[0] = m; p[1] = ssum; }
    reinterpret_cast<float4*>(p + 4)[l16] = o;
  }
}

// ---------------------------------------------------------------------------
// Combine 256 partials per head: 20 blocks x 256 threads.
// Thread t owns record t's (M,S); wave w accumulates o over records [64w,64w+64).
// ---------------------------------------------------------------------------
__global__ __launch_bounds__(256) void attn_combine(
    const float* __restrict__ part, float* __restrict__ attn_out) {
  int h = blockIdx.x;
  int tid = threadIdx.x;
  int w = tid >> 6, lane = tid & 63;
  const float* p = part + (size_t)h * NREC * PREC;

  __shared__ float fsh[NREC];
  __shared__ float redM[4], redS[4];
  __shared__ float osum[4][HDIM];

  float mt = p[tid * PREC];
  float st = p[tid * PREC + 1];
  float m = mt;
#pragma unroll
  for (int msk = 32; msk > 0; msk >>= 1) m = fmaxf(m, __shfl_xor(m, msk));
  if (lane == 0) redM[w] = m;
  __syncthreads();
  float Mg = fmaxf(fmaxf(redM[0], redM[1]), fmaxf(redM[2], redM[3]));

  float f = __expf(mt - Mg);
  fsh[tid] = f;
  float sc = st * f;
#pragma unroll
  for (int msk = 32; msk > 0; msk >>= 1) sc += __shfl_xor(sc, msk);
  if (lane == 0) redS[w] = sc;
  __syncthreads();
  float Sg = redS[0] + redS[1] + redS[2] + redS[3];

  // o[lane] accumulated over this wave's 64 records (coalesced 256B reads)
  float o = 0.f;
#pragma unroll
  for (int r = 0; r < 64; ++r) {
    int rec = w * 64 + r;
    o += fsh[rec] * p[rec * PREC + 4 + lane];
  }
  osum[w][lane] = o;
  __syncthreads();
  if (w == 0) {
    float oo = osum[0][lane] + osum[1][lane] + osum[2][lane] + osum[3][lane];
    attn_out[h * HDIM + lane] = oo / Sg;
  }
}

// ---------------------------------------------------------------------------

extern "C" void kernel_launch(void* const* d_in, const int* in_sizes, int n_in,
                              void* d_out, int out_size, void* d_ws, size_t ws_size,
                              hipStream_t stream) {
  const float* hs    = (const float*)d_in[0];  // [1280]
  const float* Kc    = (const float*)d_in[1];  // [20,8192,64]
  const float* Vc    = (const float*)d_in[2];  // [20,8192,64]
  const float* q_w   = (const float*)d_in[3];  // [1280,1280]
  const float* q_b   = (const float*)d_in[4];  // [1280]
  const float* out_w = (const float*)d_in[5];  // [1280,1280]
  const float* out_b = (const float*)d_in[6];  // [1280]
  float* out = (float*)d_out;                  // [1280]

  float* ws = (float*)d_ws;
  float* qv       = ws;                 // 1280
  float* attn_out = ws + EMBED;         // 1280
  float* part     = ws + 2 * EMBED;     // 20*256*72 floats (16B-aligned)

  // 1. q projection (+ scale)
  matvec_row<<<EMBED, 256, 0, stream>>>(q_w, hs, q_b, qv, QSCALE);
  // 2. flash-decode partials (wave-independent, no barriers)
  attn_partial<<<NHEAD * NBLK, 256, 0, stream>>>(Kc, Vc, qv, part);
  // 3. combine 256 records per head
  attn_combine<<<NHEAD, 256, 0, stream>>>(part, attn_out);
  // 4. output projection
  matvec_row<<<EMBED, 256, 0, stream>>>(out_w, attn_out, out_b, out, 1.0f);
}